// Round 5
// baseline (434.272 us; speedup 1.0000x reference)
//
#include <hip/hip_runtime.h>
#include <hip/hip_bf16.h>

// Pipeline:
//  x (4,64,130,130) --conv3x3 valid + bias + maxpool2x2--> p1 (4,64,64,64)
//  p1 --1x1 conv (64->32)--> t2 (4,32,64,64)
//  t2 --3x3 conv pad=1 (32->32)--> t3 (4,32,64,64)
//  t3 --1x1 conv (32->1152)--> t4 (4,1152,4096)  [CHANNEL-major offset field]
//  deform_conv(x, upsample2x(offsets), wd) -> out (4,64,128,128)
//  Deform: offsets at half res => 2x2 output quad shares (fy,fx); 16 bilinear
//  taps collapse to a 3x3 grid. Block = strip of 8 po; 8 blocks/CU (32 waves)
//  for latency hiding. XCD-swizzled so one quad-row's strips share an XCD L2.

#define HX 130
#define WX 130

// ---------------- K0: wd (o,c,3,3) -> wdt2[(c*9+k)*64 + o]  (k-major)
__global__ __launch_bounds__(256) void k_wdt(const float* __restrict__ wd,
                                             float* __restrict__ wdt2) {
    int idx = blockIdx.x * 256 + threadIdx.x;   // 64*64*9 = 36864
    if (idx >= 36864) return;
    int k = idx % 9;
    int rem = idx / 9;        // o*64 + c
    int c = rem & 63;
    int o = rem >> 6;
    wdt2[(c * 9 + k) * 64 + o] = wd[idx];
}

// ---------------- K1: conv3x3 valid (64->64) + bias + maxpool 2x2 -> p1
// grid 1024; block 256 = 4 pooled rows x 64 cols; 4 out-channels per block.
// LDS reads as float2 pairs -> ds_read2_b64 (4 DS instr/ci instead of 16).
__global__ __launch_bounds__(256) void k_conv0_pool(const float* __restrict__ x,
                                                    const float* __restrict__ w0,
                                                    const float* __restrict__ b0,
                                                    float* __restrict__ p1) {
    int idx = blockIdx.x;
    int xcd = idx & 7;
    int r = idx >> 3;
    int cog = r & 15;             // blockIdx-derived -> weight loads scalar
    int phi = r >> 4;             // 0..7
    int p = phi * 8 + xcd;        // 0..63 (b,tile)
    int b = p >> 4;
    int tile = p & 15;
    int tid = threadIdx.x;
    int pw = tid & 63;
    int phl = tid >> 6;           // 0..3
    int ph = tile * 4 + phl;
    __shared__ float slab[10 * WX];
    const float* xb = x + (size_t)(b * 64) * HX * WX;
    int row0 = tile * 8;
    const float* xbase = xb + row0 * WX;
    float acc[4][4];
    #pragma unroll
    for (int i = 0; i < 4; ++i)
        #pragma unroll
        for (int j = 0; j < 4; ++j) acc[i][j] = 0.f;

    float pre[6];
    #pragma unroll
    for (int j = 0; j < 6; ++j) {
        int i = tid + j * 256;
        pre[j] = (i < 10 * WX) ? xbase[i] : 0.f;
    }

    for (int ci = 0; ci < 64; ++ci) {
        __syncthreads();
        #pragma unroll
        for (int j = 0; j < 6; ++j) {
            int i = tid + j * 256;
            if (i < 10 * WX) slab[i] = pre[j];
        }
        __syncthreads();
        if (ci < 63) {
            const float* xp = xbase + (size_t)(ci + 1) * (HX * WX);
            #pragma unroll
            for (int j = 0; j < 6; ++j) {
                int i = tid + j * 256;
                pre[j] = (i < 10 * WX) ? xp[i] : 0.f;
            }
        }
        float v[4][4];
        #pragma unroll
        for (int r2 = 0; r2 < 4; ++r2) {
            const float* rp = &slab[(2 * phl + r2) * WX + 2 * pw];  // 8B aligned
            float2 a = *(const float2*)rp;
            float2 bb = *(const float2*)(rp + 2);
            v[r2][0] = a.x; v[r2][1] = a.y; v[r2][2] = bb.x; v[r2][3] = bb.y;
        }
        #pragma unroll
        for (int i = 0; i < 4; ++i) {
            const float* wp = w0 + (((cog * 4 + i) * 64) + ci) * 9;  // uniform
            float w[9];
            #pragma unroll
            for (int k = 0; k < 9; ++k) w[k] = wp[k];
            #pragma unroll
            for (int dr = 0; dr < 2; ++dr)
                #pragma unroll
                for (int dc = 0; dc < 2; ++dc) {
                    float s = acc[i][dr * 2 + dc];
                    #pragma unroll
                    for (int ky = 0; ky < 3; ++ky)
                        #pragma unroll
                        for (int kx = 0; kx < 3; ++kx)
                            s += w[ky * 3 + kx] * v[dr + ky][dc + kx];
                    acc[i][dr * 2 + dc] = s;
                }
        }
    }
    #pragma unroll
    for (int i = 0; i < 4; ++i) {
        float m = fmaxf(fmaxf(acc[i][0], acc[i][1]), fmaxf(acc[i][2], acc[i][3]))
                + b0[cog * 4 + i];
        p1[(((size_t)b * 64 + cog * 4 + i) * 64 + ph) * 64 + pw] = m;
    }
}

// ---------------- K2: 1x1 conv 64->32 on 64x64; grid 512
__global__ __launch_bounds__(256) void k_conv1x1_a(const float* __restrict__ p1,
                                                   const float* __restrict__ w1,
                                                   const float* __restrict__ b1,
                                                   float* __restrict__ t2) {
    int blk = blockIdx.x;
    int pt = blk & 15;
    int cog = (blk >> 4) & 7;
    int b = blk >> 7;
    int p = pt * 256 + threadIdx.x;
    float acc[4];
    #pragma unroll
    for (int i = 0; i < 4; ++i) acc[i] = b1[cog * 4 + i];
    const float* ip = p1 + (size_t)b * 64 * 4096 + p;
    for (int ci = 0; ci < 64; ++ci) {
        float v = ip[(size_t)ci * 4096];
        #pragma unroll
        for (int i = 0; i < 4; ++i) acc[i] += w1[(cog * 4 + i) * 64 + ci] * v;
    }
    float* op = t2 + (size_t)b * 32 * 4096 + p;
    #pragma unroll
    for (int i = 0; i < 4; ++i) op[(size_t)(cog * 4 + i) * 4096] = acc[i];
}

// ---------------- K3: 3x3 conv pad=1, 32->32 on 64x64; grid 512
__global__ __launch_bounds__(256) void k_conv3x3_b(const float* __restrict__ t2,
                                                   const float* __restrict__ w2,
                                                   const float* __restrict__ b2,
                                                   float* __restrict__ t3) {
    int blk = blockIdx.x;
    int pt = blk & 15;
    int cog = (blk >> 4) & 7;
    int b = blk >> 7;
    int p = pt * 256 + threadIdx.x;
    int hy = p >> 6, wx = p & 63;
    float acc[4];
    #pragma unroll
    for (int i = 0; i < 4; ++i) acc[i] = b2[cog * 4 + i];
    const float* ip = t2 + (size_t)b * 32 * 4096;
    for (int ci = 0; ci < 32; ++ci) {
        float v[9];
        #pragma unroll
        for (int ky = 0; ky < 3; ++ky) {
            int yy = hy + ky - 1;
            #pragma unroll
            for (int kx = 0; kx < 3; ++kx) {
                int xx = wx + kx - 1;
                bool ok = (yy >= 0 && yy < 64 && xx >= 0 && xx < 64);
                int yc = min(max(yy, 0), 63), xc = min(max(xx, 0), 63);
                float val = ip[(size_t)ci * 4096 + yc * 64 + xc];
                v[ky * 3 + kx] = ok ? val : 0.f;
            }
        }
        #pragma unroll
        for (int i = 0; i < 4; ++i) {
            const float* wp = w2 + (((cog * 4 + i) * 32) + ci) * 9;   // uniform
            float s = acc[i];
            #pragma unroll
            for (int k = 0; k < 9; ++k) s += wp[k] * v[k];
            acc[i] = s;
        }
    }
    float* op = t3 + (size_t)b * 32 * 4096 + p;
    #pragma unroll
    for (int i = 0; i < 4; ++i) op[(size_t)(cog * 4 + i) * 4096] = acc[i];
}

// ---------------- K4: 1x1 conv 32->1152, CHANNEL-major t4[b][1152][4096]
// grid 4608 = b(4)*chg(72 groups of 16 ch)*pt(16)
__global__ __launch_bounds__(256) void k_conv1x1_off(const float* __restrict__ t3,
                                                     const float* __restrict__ w3,
                                                     const float* __restrict__ b3,
                                                     float* __restrict__ t4) {
    int blk = blockIdx.x;
    int pt = blk & 15;
    int rem = blk >> 4;           // 0..287
    int chg = rem % 72;           // blockIdx-derived -> scalar weight loads
    int b = rem / 72;
    int p = pt * 256 + threadIdx.x;
    float v[32];
    const float* ip = t3 + (size_t)b * 32 * 4096 + p;
    #pragma unroll
    for (int ci = 0; ci < 32; ++ci) v[ci] = ip[(size_t)ci * 4096];
    float* op = t4 + ((size_t)b * 1152) * 4096 + p;
    #pragma unroll
    for (int j = 0; j < 16; ++j) {
        int ch = chg * 16 + j;
        float acc = b3[ch];
        const float* wp = w3 + ch * 32;      // uniform
        #pragma unroll
        for (int ci = 0; ci < 32; ++ci) acc += wp[ci] * v[ci];
        op[(size_t)ch * 4096] = acc;         // coalesced
    }
}

// ---------------- K5: deformable conv, strip-tiled two-phase LDS structure
// grid 2048 = b(4) * qrow-group(8) * strip(8) * qrow-low(8) [XCD swizzle:
// blk&7 = row low bits -> all 8 strips of one quad-row share an XCD].
// Block: 8 consecutive po; tid: og = tid>>3 (32 groups of 2 oc), q = tid&7.
// 14 KB LDS, <=64 VGPR -> 8 blocks/CU = 32 waves/CU.
#define VP 292   // vlds quad pitch in floats (72*4 + 4 pad)
__global__ __launch_bounds__(256, 8) void k_deform(const float* __restrict__ x,
                                                   const float* __restrict__ t4,
                                                   const float* __restrict__ wdt2,
                                                   float* __restrict__ out) {
    int blk = blockIdx.x;
    int rlow = blk & 7;
    int s = (blk >> 3) & 7;
    int rg = (blk >> 6) & 7;
    int b = blk >> 9;
    int qy = rg * 8 + rlow;       // quad row 0..63
    int qx0 = s * 8;              // first quad col of strip
    int po0 = qy * 64 + qx0;
    int tid = threadIdx.x;
    int og = tid >> 3;            // 0..31 (2 out-channels each)
    int q = tid & 7;              // quad in strip

    __shared__ float ofs[144 * 8];                 // [srow][q]  4608 B
    __shared__ __align__(16) float vlds[8 * VP];   // [q][ckk*4(+pad)] 9344 B

    float acc[2][4];
    #pragma unroll
    for (int o = 0; o < 2; ++o)
        #pragma unroll
        for (int ss = 0; ss < 4; ++ss) acc[o][ss] = 0.f;

    const float* xb = x + (size_t)b * 64 * HX * WX;
    const float* t4b = t4 + (size_t)b * 1152 * 4096 + po0;

    // prefetch chunk-0 offsets: 1152 floats, <=5 per thread
    float pre[5];
    #pragma unroll
    for (int j = 0; j < 5; ++j) {
        int i2 = j * 256 + tid;
        if (i2 < 1152) pre[j] = t4b[(size_t)(i2 >> 3) * 4096 + (i2 & 7)];
    }

    for (int chunk = 0; chunk < 8; ++chunk) {
        __syncthreads();          // prev phase1 done w/ ofs, prev phase2 done w/ vlds
        #pragma unroll
        for (int j = 0; j < 5; ++j) {
            int i2 = j * 256 + tid;
            if (i2 < 1152) ofs[i2] = pre[j];
        }
        if (chunk < 7) {
            const float* src = t4b + (size_t)(chunk + 1) * 144 * 4096;
            #pragma unroll
            for (int j = 0; j < 5; ++j) {
                int i2 = j * 256 + tid;
                if (i2 < 1152) pre[j] = src[(size_t)(i2 >> 3) * 4096 + (i2 & 7)];
            }
        }
        __syncthreads();          // ofs visible

        // ---- phase 1: 576 tasks (8 q x 72 ckk), q-fast lanes
        #pragma unroll
        for (int it = 0; it < 3; ++it) {
            int idx = it * 256 + tid;
            if (idx < 576) {
                int tq = idx & 7;
                int ckk = idx >> 3;               // 0..71 = ch*9+kk
                int ch = (ckk * 57) >> 9;         // /9
                int kk = ckk - ch * 9;
                int c = chunk * 8 + ch;
                float oy = ofs[(2 * ckk) * 8 + tq];
                float ox = ofs[(2 * ckk + 1) * 8 + tq];
                float py = oy + (float)(2 * qy + kk / 3);
                float px = ox + (float)(2 * (qx0 + tq) + kk % 3);
                float y0f = floorf(py), x0f = floorf(px);
                float fy = py - y0f, fx = px - x0f;
                int y0 = (int)y0f, x0 = (int)x0f;
                const float* xp = xb + (size_t)c * (HX * WX);
                float t[3][3];
                #pragma unroll
                for (int r = 0; r < 3; ++r) {
                    int yy = y0 + r;
                    bool vy = (yy >= 0) & (yy < HX);
                    int yc = min(max(yy, 0), HX - 1);
                    #pragma unroll
                    for (int sx = 0; sx < 3; ++sx) {
                        int xx = x0 + sx;
                        bool vx = (xx >= 0) & (xx < WX);
                        int xc = min(max(xx, 0), WX - 1);
                        float val = xp[yc * WX + xc];
                        t[r][sx] = (vy & vx) ? val : 0.f;
                    }
                }
                float h0[3], h1[3];
                #pragma unroll
                for (int r = 0; r < 3; ++r) {
                    h0[r] = t[r][0] + fx * (t[r][1] - t[r][0]);
                    h1[r] = t[r][1] + fx * (t[r][2] - t[r][1]);
                }
                float4 vv;
                vv.x = h0[0] + fy * (h0[1] - h0[0]);   // sub (0,0)
                vv.y = h1[0] + fy * (h1[1] - h1[0]);   // sub (0,1)
                vv.z = h0[1] + fy * (h0[2] - h0[1]);   // sub (1,0)
                vv.w = h1[1] + fy * (h1[2] - h1[1]);   // sub (1,1)
                *(float4*)&vlds[tq * VP + ckk * 4] = vv;
            }
        }
        __syncthreads();          // vlds visible

        // ---- phase 2: acc[2 outs][4 sub] += w * v
        for (int ch = 0; ch < 8; ++ch) {
            int c = chunk * 8 + ch;
            const float* wp = wdt2 + (size_t)(c * 9) * 64 + og * 2;
            const float* vp = &vlds[q * VP + (ch * 9) * 4];
            #pragma unroll
            for (int k = 0; k < 9; ++k) {
                float4 vv = *(const float4*)(vp + k * 4);
                float2 w2 = *(const float2*)(wp + k * 64);
                acc[0][0] += w2.x * vv.x;
                acc[0][1] += w2.x * vv.y;
                acc[0][2] += w2.x * vv.z;
                acc[0][3] += w2.x * vv.w;
                acc[1][0] += w2.y * vv.x;
                acc[1][1] += w2.y * vv.y;
                acc[1][2] += w2.y * vv.z;
                acc[1][3] += w2.y * vv.w;
            }
        }
    }
    // ---- epilogue
    int ho = 2 * qy, wo = 2 * (qx0 + q);
    #pragma unroll
    for (int o = 0; o < 2; ++o) {
        int oc = og * 2 + o;
        float* op = out + (((size_t)b * 64 + oc) * 128 + ho) * 128 + wo;
        *(float2*)op = make_float2(acc[o][0], acc[o][1]);
        *(float2*)(op + 128) = make_float2(acc[o][2], acc[o][3]);
    }
}

extern "C" void kernel_launch(void* const* d_in, const int* in_sizes, int n_in,
                              void* d_out, int out_size, void* d_ws, size_t ws_size,
                              hipStream_t stream) {
    const float* x  = (const float*)d_in[0];
    const float* w0 = (const float*)d_in[1];
    const float* b0 = (const float*)d_in[2];
    const float* w1 = (const float*)d_in[3];
    const float* b1 = (const float*)d_in[4];
    const float* w2 = (const float*)d_in[5];
    const float* b2 = (const float*)d_in[6];
    const float* w3 = (const float*)d_in[7];
    const float* b3 = (const float*)d_in[8];
    const float* wd = (const float*)d_in[9];
    float* out = (float*)d_out;

    float* ws = (float*)d_ws;
    float* p1   = ws;                        // 1,048,576
    float* t2   = p1 + 1048576;              //   524,288
    float* t3   = t2 + 524288;               //   524,288
    float* t4   = t3 + 524288;               // 18,874,368 (channel-major)
    float* wdt2 = t4 + 18874368;             //    36,864 (k-major)

    k_wdt<<<144, 256, 0, stream>>>(wd, wdt2);
    k_conv0_pool<<<1024, 256, 0, stream>>>(x, w0, b0, p1);
    k_conv1x1_a<<<512, 256, 0, stream>>>(p1, w1, b1, t2);
    k_conv3x3_b<<<512, 256, 0, stream>>>(t2, w2, b2, t3);
    k_conv1x1_off<<<4608, 256, 0, stream>>>(t3, w3, b3, t4);
    k_deform<<<2048, 256, 0, stream>>>(x, t4, wdt2, out);
}

// Round 6
// 371.538 us; speedup vs baseline: 1.1688x; 1.1688x over previous
//
#include <hip/hip_runtime.h>
#include <hip/hip_bf16.h>

// Pipeline:
//  x (4,64,130,130) --conv3x3 valid + bias + maxpool2x2--> p1 (4,64,64,64)
//  p1 --1x1 conv (64->32)--> t2 (4,32,64,64)
//  t2 --3x3 conv pad=1 (32->32)--> t3 (4,32,64,64)
//  t3 --1x1 conv (32->1152)--> t4 (4,1152,4096)  [CHANNEL-major offset field]
//  deform_conv(x, upsample2x(offsets), wd) -> atomicAdd into out (4,64,128,128)
//  Deform: offsets at half res => 2x2 quad shares (fy,fx); 16 bilinear taps
//  collapse to a 3x3 grid. Block = 16-po strip x half the input channels
//  (c-split 2 -> 2048 blocks = 8/CU) ; 4 oc/thread keeps 16 FMA per LDS read.

#define HX 130
#define WX 130

// ---------------- K0: wd (o,c,3,3) -> wdt2[(c*9+k)*64 + o]  (k-major)
__global__ __launch_bounds__(256) void k_wdt(const float* __restrict__ wd,
                                             float* __restrict__ wdt2) {
    int idx = blockIdx.x * 256 + threadIdx.x;   // 64*64*9 = 36864
    if (idx >= 36864) return;
    int k = idx % 9;
    int rem = idx / 9;        // o*64 + c
    int c = rem & 63;
    int o = rem >> 6;
    wdt2[(c * 9 + k) * 64 + o] = wd[idx];
}

// ---------------- K1: conv3x3 valid (64->64) + bias + maxpool 2x2 -> p1
// grid 2048 = b(4) * cog(16, 4 oc) * tile(32, 2 pooled rows); block 128.
// 3 KB LDS -> 16 blocks/CU.
__global__ __launch_bounds__(128, 8) void k_conv0_pool(const float* __restrict__ x,
                                                       const float* __restrict__ w0,
                                                       const float* __restrict__ b0,
                                                       float* __restrict__ p1) {
    int idx = blockIdx.x;
    int tile = idx & 31;          // 2 pooled rows each
    int cog = (idx >> 5) & 15;    // blockIdx-derived -> weight loads scalar
    int b = idx >> 9;
    int tid = threadIdx.x;
    int pw = tid & 63;
    int phl = tid >> 6;           // 0..1
    int ph = tile * 2 + phl;
    __shared__ float slab[6 * WX];            // 780 floats
    const float* xb = x + (size_t)(b * 64) * HX * WX;
    int row0 = tile * 4;          // x rows row0..row0+5
    const float* xbase = xb + row0 * WX;
    float acc[4][4];
    #pragma unroll
    for (int i = 0; i < 4; ++i)
        #pragma unroll
        for (int j = 0; j < 4; ++j) acc[i][j] = 0.f;

    float pre[7];
    #pragma unroll
    for (int j = 0; j < 7; ++j) {
        int i = tid + j * 128;
        pre[j] = (i < 6 * WX) ? xbase[i] : 0.f;
    }

    for (int ci = 0; ci < 64; ++ci) {
        __syncthreads();
        #pragma unroll
        for (int j = 0; j < 7; ++j) {
            int i = tid + j * 128;
            if (i < 6 * WX) slab[i] = pre[j];
        }
        __syncthreads();
        if (ci < 63) {
            const float* xp = xbase + (size_t)(ci + 1) * (HX * WX);
            #pragma unroll
            for (int j = 0; j < 7; ++j) {
                int i = tid + j * 128;
                pre[j] = (i < 6 * WX) ? xp[i] : 0.f;
            }
        }
        float v[4][4];
        #pragma unroll
        for (int r2 = 0; r2 < 4; ++r2) {
            const float* rp = &slab[(2 * phl + r2) * WX + 2 * pw];  // 8B aligned
            float2 a = *(const float2*)rp;
            float2 bb = *(const float2*)(rp + 2);
            v[r2][0] = a.x; v[r2][1] = a.y; v[r2][2] = bb.x; v[r2][3] = bb.y;
        }
        #pragma unroll
        for (int i = 0; i < 4; ++i) {
            const float* wp = w0 + (((cog * 4 + i) * 64) + ci) * 9;  // uniform
            float w[9];
            #pragma unroll
            for (int k = 0; k < 9; ++k) w[k] = wp[k];
            #pragma unroll
            for (int dr = 0; dr < 2; ++dr)
                #pragma unroll
                for (int dc = 0; dc < 2; ++dc) {
                    float s = acc[i][dr * 2 + dc];
                    #pragma unroll
                    for (int ky = 0; ky < 3; ++ky)
                        #pragma unroll
                        for (int kx = 0; kx < 3; ++kx)
                            s += w[ky * 3 + kx] * v[dr + ky][dc + kx];
                    acc[i][dr * 2 + dc] = s;
                }
        }
    }
    #pragma unroll
    for (int i = 0; i < 4; ++i) {
        float m = fmaxf(fmaxf(acc[i][0], acc[i][1]), fmaxf(acc[i][2], acc[i][3]))
                + b0[cog * 4 + i];
        p1[(((size_t)b * 64 + cog * 4 + i) * 64 + ph) * 64 + pw] = m;
    }
}

// ---------------- K2: 1x1 conv 64->32 on 64x64; grid 1024 (2 oc/thread)
__global__ __launch_bounds__(256) void k_conv1x1_a(const float* __restrict__ p1,
                                                   const float* __restrict__ w1,
                                                   const float* __restrict__ b1,
                                                   float* __restrict__ t2) {
    int blk = blockIdx.x;
    int pt = blk & 15;
    int cog = (blk >> 4) & 15;
    int b = blk >> 8;
    int p = pt * 256 + threadIdx.x;
    float acc[2];
    #pragma unroll
    for (int i = 0; i < 2; ++i) acc[i] = b1[cog * 2 + i];
    const float* ip = p1 + (size_t)b * 64 * 4096 + p;
    for (int ci = 0; ci < 64; ++ci) {
        float v = ip[(size_t)ci * 4096];
        #pragma unroll
        for (int i = 0; i < 2; ++i) acc[i] += w1[(cog * 2 + i) * 64 + ci] * v;
    }
    float* op = t2 + (size_t)b * 32 * 4096 + p;
    #pragma unroll
    for (int i = 0; i < 2; ++i) op[(size_t)(cog * 2 + i) * 4096] = acc[i];
}

// ---------------- K3: 3x3 conv pad=1, 32->32 on 64x64; grid 1024 (2 oc/thread)
__global__ __launch_bounds__(256) void k_conv3x3_b(const float* __restrict__ t2,
                                                   const float* __restrict__ w2,
                                                   const float* __restrict__ b2,
                                                   float* __restrict__ t3) {
    int blk = blockIdx.x;
    int pt = blk & 15;
    int cog = (blk >> 4) & 15;
    int b = blk >> 8;
    int p = pt * 256 + threadIdx.x;
    int hy = p >> 6, wx = p & 63;
    float acc[2];
    #pragma unroll
    for (int i = 0; i < 2; ++i) acc[i] = b2[cog * 2 + i];
    const float* ip = t2 + (size_t)b * 32 * 4096;
    for (int ci = 0; ci < 32; ++ci) {
        float v[9];
        #pragma unroll
        for (int ky = 0; ky < 3; ++ky) {
            int yy = hy + ky - 1;
            #pragma unroll
            for (int kx = 0; kx < 3; ++kx) {
                int xx = wx + kx - 1;
                bool ok = (yy >= 0 && yy < 64 && xx >= 0 && xx < 64);
                int yc = min(max(yy, 0), 63), xc = min(max(xx, 0), 63);
                float val = ip[(size_t)ci * 4096 + yc * 64 + xc];
                v[ky * 3 + kx] = ok ? val : 0.f;
            }
        }
        #pragma unroll
        for (int i = 0; i < 2; ++i) {
            const float* wp = w2 + (((cog * 2 + i) * 32) + ci) * 9;   // uniform
            float s = acc[i];
            #pragma unroll
            for (int k = 0; k < 9; ++k) s += wp[k] * v[k];
            acc[i] = s;
        }
    }
    float* op = t3 + (size_t)b * 32 * 4096 + p;
    #pragma unroll
    for (int i = 0; i < 2; ++i) op[(size_t)(cog * 2 + i) * 4096] = acc[i];
}

// ---------------- K4: 1x1 conv 32->1152, CHANNEL-major t4[b][1152][4096]
// grid 4608 = b(4)*chg(72 groups of 16 ch)*pt(16)
__global__ __launch_bounds__(256) void k_conv1x1_off(const float* __restrict__ t3,
                                                     const float* __restrict__ w3,
                                                     const float* __restrict__ b3,
                                                     float* __restrict__ t4) {
    int blk = blockIdx.x;
    int pt = blk & 15;
    int rem = blk >> 4;           // 0..287
    int chg = rem % 72;           // blockIdx-derived -> scalar weight loads
    int b = rem / 72;
    int p = pt * 256 + threadIdx.x;
    float v[32];
    const float* ip = t3 + (size_t)b * 32 * 4096 + p;
    #pragma unroll
    for (int ci = 0; ci < 32; ++ci) v[ci] = ip[(size_t)ci * 4096];
    float* op = t4 + ((size_t)b * 1152) * 4096 + p;
    #pragma unroll
    for (int j = 0; j < 16; ++j) {
        int ch = chg * 16 + j;
        float acc = b3[ch];
        const float* wp = w3 + ch * 32;      // uniform
        #pragma unroll
        for (int ci = 0; ci < 32; ++ci) acc += wp[ci] * v[ci];
        op[(size_t)ch * 4096] = acc;         // coalesced
    }
}

// ---------------- K5: deformable conv, strip + input-channel split
// grid 2048 = b(4) * half(2) * strip(256 of 16 po); block 256 = og(16 x 4oc) x q(16)
// Each block does 4 chunks (32 input ch); halves combine via atomicAdd (out
// zeroed by hipMemsetAsync first). 18.7 KB LDS, 64 VGPR -> 8 blocks/CU.
#define VP 292   // vlds quad pitch in floats (72*4 + 4) -> only 2-way (free) conflicts
__global__ __launch_bounds__(256, 8) void k_deform(const float* __restrict__ x,
                                                   const float* __restrict__ t4,
                                                   const float* __restrict__ wdt2,
                                                   float* __restrict__ out) {
    int blk = blockIdx.x;
    int strip = blk & 255;
    int half = (blk >> 8) & 1;
    int b = blk >> 9;
    int tid = threadIdx.x;
    int og = tid >> 4;            // 0..15 (4 out-channels each)
    int q = tid & 15;             // quad in strip
    int po0 = strip * 16;
    int qy = po0 >> 6;            // strip lies in one quad-row
    int qx0 = po0 & 63;

    __shared__ __align__(16) float vlds[16 * VP];   // [q][ckk*4(+pad)] 18688 B

    float acc[4][4];
    #pragma unroll
    for (int o = 0; o < 4; ++o)
        #pragma unroll
        for (int s = 0; s < 4; ++s) acc[o][s] = 0.f;

    const float* xb = x + (size_t)b * 64 * HX * WX;
    const float* t4b = t4 + (size_t)b * 1152 * 4096 + po0;

    for (int c4 = 0; c4 < 4; ++c4) {
        int chunk = half * 4 + c4;
        __syncthreads();          // prev phase2 done with vlds
        // ---- phase 1: 1152 tasks (16 q x 72 ckk); offsets read direct
        // (channel-major t4 -> 64B-coalesced per 16 lanes)
        #pragma unroll
        for (int it = 0; it < 5; ++it) {
            int idx = it * 256 + tid;
            if (idx < 1152) {
                int tq = idx & 15;
                int ckk = idx >> 4;               // 0..71 = ch*9+kk
                int ch = (ckk * 57) >> 9;         // /9
                int kk = ckk - ch * 9;
                int c = chunk * 8 + ch;
                float oy = t4b[(size_t)(chunk * 144 + 2 * ckk) * 4096 + tq];
                float ox = t4b[(size_t)(chunk * 144 + 2 * ckk + 1) * 4096 + tq];
                float py = oy + (float)(2 * qy + kk / 3);
                float px = ox + (float)(2 * (qx0 + tq) + kk % 3);
                float y0f = floorf(py), x0f = floorf(px);
                float fy = py - y0f, fx = px - x0f;
                int y0 = (int)y0f, x0 = (int)x0f;
                const float* xp = xb + (size_t)c * (HX * WX);
                float t[3][3];
                #pragma unroll
                for (int r = 0; r < 3; ++r) {
                    int yy = y0 + r;
                    bool vy = (yy >= 0) & (yy < HX);
                    int yc = min(max(yy, 0), HX - 1);
                    #pragma unroll
                    for (int sx = 0; sx < 3; ++sx) {
                        int xx = x0 + sx;
                        bool vx = (xx >= 0) & (xx < WX);
                        int xc = min(max(xx, 0), WX - 1);
                        float val = xp[yc * WX + xc];
                        t[r][sx] = (vy & vx) ? val : 0.f;
                    }
                }
                float h0[3], h1[3];
                #pragma unroll
                for (int r = 0; r < 3; ++r) {
                    h0[r] = t[r][0] + fx * (t[r][1] - t[r][0]);
                    h1[r] = t[r][1] + fx * (t[r][2] - t[r][1]);
                }
                float4 vv;
                vv.x = h0[0] + fy * (h0[1] - h0[0]);   // sub (0,0)
                vv.y = h1[0] + fy * (h1[1] - h1[0]);   // sub (0,1)
                vv.z = h0[1] + fy * (h0[2] - h0[1]);   // sub (1,0)
                vv.w = h1[1] + fy * (h1[2] - h1[1]);   // sub (1,1)
                *(float4*)&vlds[tq * VP + ckk * 4] = vv;
            }
        }
        __syncthreads();          // vlds visible

        // ---- phase 2: acc[4 outs][4 sub] += w * v  (16 FMA per b128 read)
        for (int ch = 0; ch < 8; ++ch) {
            int c = chunk * 8 + ch;
            const float* wp = wdt2 + (size_t)(c * 9) * 64 + og * 4;
            const float* vp = &vlds[q * VP + (ch * 9) * 4];
            #pragma unroll
            for (int k = 0; k < 9; ++k) {
                float4 vv = *(const float4*)(vp + k * 4);
                float4 w4 = *(const float4*)(wp + k * 64);
                float wv[4] = {w4.x, w4.y, w4.z, w4.w};
                #pragma unroll
                for (int o = 0; o < 4; ++o) {
                    acc[o][0] += wv[o] * vv.x;
                    acc[o][1] += wv[o] * vv.y;
                    acc[o][2] += wv[o] * vv.z;
                    acc[o][3] += wv[o] * vv.w;
                }
            }
        }
    }
    // ---- epilogue: accumulate the two c-halves (2-way, zero contention)
    int ho = 2 * qy, wo = 2 * (qx0 + q);
    #pragma unroll
    for (int o = 0; o < 4; ++o) {
        int oc = og * 4 + o;
        float* op = out + (((size_t)b * 64 + oc) * 128 + ho) * 128 + wo;
        atomicAdd(op,       acc[o][0]);
        atomicAdd(op + 1,   acc[o][1]);
        atomicAdd(op + 128, acc[o][2]);
        atomicAdd(op + 129, acc[o][3]);
    }
}

extern "C" void kernel_launch(void* const* d_in, const int* in_sizes, int n_in,
                              void* d_out, int out_size, void* d_ws, size_t ws_size,
                              hipStream_t stream) {
    const float* x  = (const float*)d_in[0];
    const float* w0 = (const float*)d_in[1];
    const float* b0 = (const float*)d_in[2];
    const float* w1 = (const float*)d_in[3];
    const float* b1 = (const float*)d_in[4];
    const float* w2 = (const float*)d_in[5];
    const float* b2 = (const float*)d_in[6];
    const float* w3 = (const float*)d_in[7];
    const float* b3 = (const float*)d_in[8];
    const float* wd = (const float*)d_in[9];
    float* out = (float*)d_out;

    float* ws = (float*)d_ws;
    float* p1   = ws;                        // 1,048,576
    float* t2   = p1 + 1048576;              //   524,288
    float* t3   = t2 + 524288;               //   524,288
    float* t4   = t3 + 524288;               // 18,874,368 (channel-major)
    float* wdt2 = t4 + 18874368;             //    36,864 (k-major)

    // zero out for the deform atomic accumulation (graph-capturable)
    hipMemsetAsync(out, 0, (size_t)out_size * sizeof(float), stream);

    k_wdt<<<144, 256, 0, stream>>>(wd, wdt2);
    k_conv0_pool<<<2048, 128, 0, stream>>>(x, w0, b0, p1);
    k_conv1x1_a<<<1024, 256, 0, stream>>>(p1, w1, b1, t2);
    k_conv3x3_b<<<1024, 256, 0, stream>>>(t2, w2, b2, t3);
    k_conv1x1_off<<<4608, 256, 0, stream>>>(t3, w3, b3, t4);
    k_deform<<<2048, 256, 0, stream>>>(x, t4, wdt2, out);
}